// Round 2
// baseline (1089.748 us; speedup 1.0000x reference)
//
#include <hip/hip_runtime.h>
#include <math.h>

#define N_NODES 50000
#define N_EDGES 800000
#define IN_CH 32
#define HIDC 64
#define EDIM 16

typedef unsigned short u16;
typedef unsigned int u32;
typedef _Float16 f16;

__device__ __forceinline__ u16 f2bf(float f) {
    u32 u = __float_as_uint(f);
    u32 lsb = (u >> 16) & 1u;
    u += 0x7fffu + lsb;
    return (u16)(u >> 16);
}

// ---------------- K0: edge MLP  e = gelu(attr@Wm1+bm1)@Wm2+bm2 ----------------
__global__ void k_edge_mlp(const float* __restrict__ edge_attr,
                           const float* __restrict__ Wm1, const float* __restrict__ bm1,
                           const float* __restrict__ Wm2, const float* __restrict__ bm2,
                           float* __restrict__ e_buf) {
    int e = blockIdx.x * blockDim.x + threadIdx.x;
    if (e >= N_EDGES) return;
    const float4* ap = (const float4*)(edge_attr + (size_t)e * 16);
    float a[16];
    #pragma unroll
    for (int i = 0; i < 4; i++) {
        float4 r = ap[i];
        a[4*i] = r.x; a[4*i+1] = r.y; a[4*i+2] = r.z; a[4*i+3] = r.w;
    }
    float g1[16];
    #pragma unroll
    for (int j = 0; j < 16; j++) {
        float v = bm1[j];
        #pragma unroll
        for (int k = 0; k < 16; k++) v = fmaf(a[k], Wm1[k*16 + j], v);
        g1[j] = 0.5f * v * (1.0f + erff(v * 0.70710678118654752f));
    }
    float o[16];
    #pragma unroll
    for (int j = 0; j < 16; j++) {
        float v = bm2[j];
        #pragma unroll
        for (int k = 0; k < 16; k++) v = fmaf(g1[k], Wm2[k*16 + j], v);
        o[j] = v;
    }
    float4* op = (float4*)(e_buf + (size_t)e * 16);
    op[0] = make_float4(o[0], o[1], o[2], o[3]);
    op[1] = make_float4(o[4], o[5], o[6], o[7]);
    op[2] = make_float4(o[8], o[9], o[10], o[11]);
    op[3] = make_float4(o[12], o[13], o[14], o[15]);
}

// ---------------- K1: node features  XL/XR[n][inst][c] (bias included) --------
// grid.y in [0,8): g = y&3, isR = y>>2.  K=32 for x-input (inst g), K=64 for h (inst 4+g).
template<int K>
__global__ void __launch_bounds__(64)
k_node_feats(const float* __restrict__ in,
             const float* __restrict__ Wl, const float* __restrict__ bl,
             const float* __restrict__ Wr, const float* __restrict__ br,
             f16* __restrict__ XL, f16* __restrict__ XR, int inst_base) {
    int g = blockIdx.y & 3;
    int isR = blockIdx.y >> 2;
    const float* W = isR ? Wr : Wl;
    const float* bias = isR ? br : bl;
    f16* out = isR ? XR : XL;
    int c = threadIdx.x;
    float wcol[K];
    #pragma unroll
    for (int k = 0; k < K; k++) wcol[k] = W[(g*K + k)*64 + c];
    float b = bias[g*64 + c];
    int inst = inst_base + g;
    for (int n = blockIdx.x; n < N_NODES; n += gridDim.x) {
        const float* row = in + (size_t)n * K;  // wave-uniform -> scalar loads
        float acc = b;
        #pragma unroll
        for (int k = 0; k < K; k++) acc = fmaf(row[k], wcol[k], acc);
        out[((size_t)n*8 + inst)*64 + c] = (f16)acc;
    }
}

// ---------------- K2: CSR build ----------------
__global__ void k_deg(const int* __restrict__ dst, int* __restrict__ deg) {
    int e = blockIdx.x * blockDim.x + threadIdx.x;
    if (e < N_EDGES) atomicAdd(&deg[dst[e]], 1);
}

__global__ void k_scan(int* __restrict__ degcur, int* __restrict__ row_ptr) {
    __shared__ int sbuf[1024];
    __shared__ int carry;
    int t = threadIdx.x;
    if (t == 0) { carry = 0; row_ptr[0] = 0; }
    __syncthreads();
    for (int base = 0; base < N_NODES; base += 1024) {
        int i = base + t;
        int v = (i < N_NODES) ? degcur[i] : 0;
        sbuf[t] = v;
        __syncthreads();
        for (int off = 1; off < 1024; off <<= 1) {
            int add = (t >= off) ? sbuf[t - off] : 0;
            __syncthreads();
            sbuf[t] += add;
            __syncthreads();
        }
        int inc = sbuf[t];
        if (i < N_NODES) { row_ptr[i + 1] = carry + inc; degcur[i] = 0; }
        __syncthreads();
        if (t == 1023) carry += sbuf[1023];
        __syncthreads();
    }
}

__global__ void k_fill(const int* __restrict__ dst, const int* __restrict__ row_ptr,
                       int* __restrict__ cursor, int* __restrict__ sorted_eid) {
    int e = blockIdx.x * blockDim.x + threadIdx.x;
    if (e < N_EDGES) {
        int d = dst[e];
        int pos = atomicAdd(&cursor[d], 1);
        sorted_eid[row_ptr[d] + pos] = e;
    }
}

// ---------------- K3: fused GATv2 x8 + LSTM + LayerNorm ----------------
// one wave (64 threads) per node; lane = output channel c; head = c>>5
__global__ void __launch_bounds__(64)
k_gat_main(const int* __restrict__ src_idx,
           const float* __restrict__ e_buf,
           const f16* __restrict__ XL, const f16* __restrict__ XR,
           const int* __restrict__ row_ptr, const int* __restrict__ sorted_eid,
           const float* __restrict__ Wex, const float* __restrict__ Weh,
           const float* __restrict__ attx, const float* __restrict__ atth,
           const float* __restrict__ biasx, const float* __restrict__ biash,
           const float* __restrict__ c_prev,
           const float* __restrict__ ln_g, const float* __restrict__ ln_b,
           float* __restrict__ out) {
    int n = blockIdx.x;
    int c = threadIdx.x;
    int hh = c >> 5;
    int ch = c & 31;

    float attv[8];
    #pragma unroll
    for (int g = 0; g < 4; g++) {
        attv[g]     = attx[(g*2 + hh)*32 + ch];
        attv[4 + g] = atth[(g*2 + hh)*32 + ch];
    }
    // We columns for this lane, packed as bf16 pairs along k (64 VGPRs).
    // ee magnitudes are ~0.05; bf16 rounding of the weights is negligible.
    u32 wepk[8][8];
    #pragma unroll
    for (int g = 0; g < 4; g++) {
        #pragma unroll
        for (int k2 = 0; k2 < 8; k2++) {
            u32 lo = f2bf(Wex[(g*16 + 2*k2)*64 + c]);
            u32 hi = f2bf(Wex[(g*16 + 2*k2 + 1)*64 + c]);
            wepk[g][k2] = lo | (hi << 16);
            lo = f2bf(Weh[(g*16 + 2*k2)*64 + c]);
            hi = f2bf(Weh[(g*16 + 2*k2 + 1)*64 + c]);
            wepk[4 + g][k2] = lo | (hi << 16);
        }
    }
    float xr8[8], acc[8], den[8];
    #pragma unroll
    for (int i = 0; i < 8; i++) {
        xr8[i] = (float)XR[((size_t)n*8 + i)*64 + c];
        acc[i] = 0.f;
        den[i] = 0.f;
    }
    int start = row_ptr[n];
    int end = row_ptr[n + 1];
    for (int ii = start; ii < end; ii++) {
        int eid = __builtin_amdgcn_readfirstlane(sorted_eid[ii]);
        int sn  = __builtin_amdgcn_readfirstlane(src_idx[eid]);
        const float* er = e_buf + (size_t)eid * 16;  // uniform -> scalar loads
        float es[16];
        #pragma unroll
        for (int k = 0; k < 16; k++) es[k] = er[k];
        const f16* xlp = XL + (size_t)sn * 512 + c;
        #pragma unroll
        for (int inst = 0; inst < 8; inst++) {
            float xls = (float)xlp[inst * 64];
            float ee = 0.f;
            #pragma unroll
            for (int k2 = 0; k2 < 8; k2++) {
                u32 w = wepk[inst][k2];
                ee = fmaf(es[2*k2],     __uint_as_float(w << 16), ee);
                ee = fmaf(es[2*k2 + 1], __uint_as_float(w & 0xffff0000u), ee);
            }
            float m = xls + xr8[inst] + ee;
            float mr = fmaxf(m, 0.f) + 0.2f * fminf(m, 0.f);  // leaky_relu
            float t = mr * attv[inst];
            #pragma unroll
            for (int off = 16; off >= 1; off >>= 1) t += __shfl_xor(t, off);
            // scores are tiny (|s| << 1): exp without max-subtraction is exact-equivalent
            float p = __expf(t);
            den[inst] += p;
            acc[inst] = fmaf(p, xls, acc[inst]);
        }
    }
    float gates[4];
    #pragma unroll
    for (int g = 0; g < 4; g++) {
        float ax = acc[g]     / (den[g]     + 1e-16f) + biasx[g*64 + c];
        float ah = acc[4 + g] / (den[4 + g] + 1e-16f) + biash[g*64 + c];
        gates[g] = ax + ah;
    }
    float it = 1.f / (1.f + __expf(-gates[0]));
    float ft = 1.f / (1.f + __expf(-gates[1]));
    float ot = 1.f / (1.f + __expf(-gates[2]));
    float gt = tanhf(gates[3]);
    float cp = c_prev[(size_t)n*64 + c];
    float ct = ft * cp + it * gt;
    float ht = ot * tanhf(ct);
    // LayerNorm over the 64 lanes
    float s1 = ht;
    #pragma unroll
    for (int off = 32; off >= 1; off >>= 1) s1 += __shfl_xor(s1, off);
    float mu = s1 * (1.f / 64.f);
    float d = ht - mu;
    float s2 = d * d;
    #pragma unroll
    for (int off = 32; off >= 1; off >>= 1) s2 += __shfl_xor(s2, off);
    float var = s2 * (1.f / 64.f);
    float y = d * rsqrtf(var + 1e-5f) * ln_g[c] + ln_b[c];
    out[(size_t)n*64 + c] = y;
    out[(size_t)(N_NODES + n)*64 + c] = ct;
}

extern "C" void kernel_launch(void* const* d_in, const int* in_sizes, int n_in,
                              void* d_out, int out_size, void* d_ws, size_t ws_size,
                              hipStream_t stream) {
    const float* x_t    = (const float*)d_in[0];
    const float* h_prev = (const float*)d_in[1];
    const float* c_prev = (const float*)d_in[2];
    const int*   ei     = (const int*)d_in[3];
    const float* eattr  = (const float*)d_in[4];
    const float* Wm1    = (const float*)d_in[5];
    const float* bm1    = (const float*)d_in[6];
    const float* Wm2    = (const float*)d_in[7];
    const float* bm2    = (const float*)d_in[8];
    const float* Wlx    = (const float*)d_in[9];
    const float* blx    = (const float*)d_in[10];
    const float* Wrx    = (const float*)d_in[11];
    const float* brx    = (const float*)d_in[12];
    const float* Wex    = (const float*)d_in[13];
    const float* attx   = (const float*)d_in[14];
    const float* biasx  = (const float*)d_in[15];
    const float* Wlh    = (const float*)d_in[16];
    const float* blh    = (const float*)d_in[17];
    const float* Wrh    = (const float*)d_in[18];
    const float* brh    = (const float*)d_in[19];
    const float* Weh    = (const float*)d_in[20];
    const float* atth   = (const float*)d_in[21];
    const float* biash  = (const float*)d_in[22];
    const float* ln_g   = (const float*)d_in[23];
    const float* ln_b   = (const float*)d_in[24];

    char* ws = (char*)d_ws;
    float* e_buf   = (float*)(ws + 0);            // 51,200,000 B
    f16*   XL      = (f16*)(ws + 51200000);       // 51,200,000 B
    f16*   XR      = (f16*)(ws + 102400000);      // 51,200,000 B
    int*   row_ptr = (int*)(ws + 153600000);      //    200,192 B
    int*   degcur  = (int*)(ws + 153800192);      //    200,192 B
    int*   sorted  = (int*)(ws + 154000384);      //  3,200,000 B  (total ~157.2 MB)

    const int* srcp = ei;
    const int* dstp = ei + N_EDGES;

    hipMemsetAsync(degcur, 0, N_NODES * sizeof(int), stream);

    k_edge_mlp<<<(N_EDGES + 255) / 256, 256, 0, stream>>>(eattr, Wm1, bm1, Wm2, bm2, e_buf);
    k_node_feats<32><<<dim3(1024, 8), 64, 0, stream>>>(x_t, Wlx, blx, Wrx, brx, XL, XR, 0);
    k_node_feats<64><<<dim3(1024, 8), 64, 0, stream>>>(h_prev, Wlh, blh, Wrh, brh, XL, XR, 4);
    k_deg<<<(N_EDGES + 255) / 256, 256, 0, stream>>>(dstp, degcur);
    k_scan<<<1, 1024, 0, stream>>>(degcur, row_ptr);
    k_fill<<<(N_EDGES + 255) / 256, 256, 0, stream>>>(dstp, row_ptr, degcur, sorted);
    k_gat_main<<<N_NODES, 64, 0, stream>>>(srcp, e_buf, XL, XR, row_ptr, sorted,
                                           Wex, Weh, attx, atth, biasx, biash,
                                           c_prev, ln_g, ln_b, (float*)d_out);
}

// Round 4
// 882.398 us; speedup vs baseline: 1.2350x; 1.2350x over previous
//
#include <hip/hip_runtime.h>
#include <math.h>

#define N_NODES 50000
#define N_EDGES 800000
#define IN_CH 32
#define HIDC 64
#define EDIM 16
#define SCAN_B 512
#define SCAN_NBLK ((N_NODES + SCAN_B - 1) / SCAN_B)   // 98

typedef unsigned short u16;
typedef unsigned int u32;
typedef _Float16 f16;
typedef __fp16 h2 __attribute__((ext_vector_type(2)));   // matches cvt_pkrtz / fdot2

// ---------------- K0: edge MLP  e = gelu(attr@Wm1+bm1)@Wm2+bm2 ----------------
__global__ void k_edge_mlp(const float* __restrict__ edge_attr,
                           const float* __restrict__ Wm1, const float* __restrict__ bm1,
                           const float* __restrict__ Wm2, const float* __restrict__ bm2,
                           float* __restrict__ e_buf) {
    int e = blockIdx.x * blockDim.x + threadIdx.x;
    if (e >= N_EDGES) return;
    const float4* ap = (const float4*)(edge_attr + (size_t)e * 16);
    float a[16];
    #pragma unroll
    for (int i = 0; i < 4; i++) {
        float4 r = ap[i];
        a[4*i] = r.x; a[4*i+1] = r.y; a[4*i+2] = r.z; a[4*i+3] = r.w;
    }
    float g1[16];
    #pragma unroll
    for (int j = 0; j < 16; j++) {
        float v = bm1[j];
        #pragma unroll
        for (int k = 0; k < 16; k++) v = fmaf(a[k], Wm1[k*16 + j], v);
        g1[j] = 0.5f * v * (1.0f + erff(v * 0.70710678118654752f));
    }
    float o[16];
    #pragma unroll
    for (int j = 0; j < 16; j++) {
        float v = bm2[j];
        #pragma unroll
        for (int k = 0; k < 16; k++) v = fmaf(g1[k], Wm2[k*16 + j], v);
        o[j] = v;
    }
    float4* op = (float4*)(e_buf + (size_t)e * 16);
    op[0] = make_float4(o[0], o[1], o[2], o[3]);
    op[1] = make_float4(o[4], o[5], o[6], o[7]);
    op[2] = make_float4(o[8], o[9], o[10], o[11]);
    op[3] = make_float4(o[12], o[13], o[14], o[15]);
}

// ---------------- K1: node features  XL/XR[n][inst][c] (bias included) --------
template<int K>
__global__ void __launch_bounds__(64)
k_node_feats(const float* __restrict__ in,
             const float* __restrict__ Wl, const float* __restrict__ bl,
             const float* __restrict__ Wr, const float* __restrict__ br,
             f16* __restrict__ XL, f16* __restrict__ XR, int inst_base) {
    int g = blockIdx.y & 3;
    int isR = blockIdx.y >> 2;
    const float* W = isR ? Wr : Wl;
    const float* bias = isR ? br : bl;
    f16* out = isR ? XR : XL;
    int c = threadIdx.x;
    float wcol[K];
    #pragma unroll
    for (int k = 0; k < K; k++) wcol[k] = W[(g*K + k)*64 + c];
    float b = bias[g*64 + c];
    int inst = inst_base + g;
    for (int n = blockIdx.x; n < N_NODES; n += gridDim.x) {
        const float* row = in + (size_t)n * K;  // wave-uniform -> scalar loads
        float acc = b;
        #pragma unroll
        for (int k = 0; k < K; k++) acc = fmaf(row[k], wcol[k], acc);
        out[((size_t)n*8 + inst)*64 + c] = (f16)acc;
    }
}

// ---------------- K2: CSR build (deg -> 3-phase scan -> fill) ----------------
__global__ void k_deg(const int* __restrict__ dst, int* __restrict__ deg) {
    int e = blockIdx.x * blockDim.x + threadIdx.x;
    if (e < N_EDGES) atomicAdd(&deg[dst[e]], 1);
}

__global__ void __launch_bounds__(SCAN_B)
k_scan1(const int* __restrict__ deg, int* __restrict__ tmp, int* __restrict__ partials) {
    __shared__ int s[SCAN_B];
    int t = threadIdx.x;
    int i = blockIdx.x * SCAN_B + t;
    int v = (i < N_NODES) ? deg[i] : 0;
    s[t] = v;
    __syncthreads();
    #pragma unroll
    for (int off = 1; off < SCAN_B; off <<= 1) {
        int add = (t >= off) ? s[t - off] : 0;
        __syncthreads();
        s[t] += add;
        __syncthreads();
    }
    if (i < N_NODES) tmp[i] = s[t];
    if (t == SCAN_B - 1) partials[blockIdx.x] = s[SCAN_B - 1];
}

__global__ void __launch_bounds__(64)
k_scan2(int* __restrict__ partials) {
    int lane = threadIdx.x;
    int carry = 0;
    for (int base = 0; base < SCAN_NBLK; base += 64) {
        int i = base + lane;
        int v = (i < SCAN_NBLK) ? partials[i] : 0;
        #pragma unroll
        for (int off = 1; off < 64; off <<= 1) {
            int u = __shfl_up(v, off);
            if (lane >= off) v += u;
        }
        if (i < SCAN_NBLK) partials[i] = v + carry;
        carry += __shfl(v, 63);
    }
}

__global__ void __launch_bounds__(SCAN_B)
k_scan3(const int* __restrict__ tmp, const int* __restrict__ partials,
        int* __restrict__ row_ptr, int* __restrict__ cursor) {
    int i = blockIdx.x * SCAN_B + threadIdx.x;
    if (i < N_NODES) {
        int b = blockIdx.x;
        int off = (b > 0) ? partials[b - 1] : 0;
        row_ptr[i + 1] = off + tmp[i];
        cursor[i] = 0;
        if (i == 0) row_ptr[0] = 0;
    }
}

__global__ void k_fill(const int* __restrict__ dst, const int* __restrict__ row_ptr,
                       int* __restrict__ cursor, int* __restrict__ sorted_eid) {
    int e = blockIdx.x * blockDim.x + threadIdx.x;
    if (e < N_EDGES) {
        int d = dst[e];
        int pos = atomicAdd(&cursor[d], 1);
        sorted_eid[row_ptr[d] + pos] = e;
    }
}

// ---------------- K3: fused GATv2 x8 + LSTM + LayerNorm ----------------
// 256-thread blocks = 4 waves; each wave owns one node; lane = output channel
__global__ void __launch_bounds__(256)
k_gat_main(const int* __restrict__ src_idx,
           const float* __restrict__ e_buf,
           const f16* __restrict__ XL, const f16* __restrict__ XR,
           const int* __restrict__ row_ptr, const int* __restrict__ sorted_eid,
           const float* __restrict__ Wex, const float* __restrict__ Weh,
           const float* __restrict__ attx, const float* __restrict__ atth,
           const float* __restrict__ biasx, const float* __restrict__ biash,
           const float* __restrict__ c_prev,
           const float* __restrict__ ln_g, const float* __restrict__ ln_b,
           float* __restrict__ out) {
    int wv = threadIdx.x >> 6;
    int lane = threadIdx.x & 63;
    int n = blockIdx.x * 4 + wv;          // 50000 = 12500*4, no remainder
    int c = lane;
    int hh = c >> 5;
    int ch = c & 31;

    float attv[8];
    #pragma unroll
    for (int g = 0; g < 4; g++) {
        attv[g]     = attx[(g*2 + hh)*32 + ch];
        attv[4 + g] = atth[(g*2 + hh)*32 + ch];
    }
    // We columns for this lane, packed f16 pairs along k (64 VGPRs), fed to v_dot2_f32_f16
    h2 wef[8][8];
    #pragma unroll
    for (int g = 0; g < 4; g++) {
        #pragma unroll
        for (int k2 = 0; k2 < 8; k2++) {
            wef[g][k2]     = __builtin_amdgcn_cvt_pkrtz(Wex[(g*16 + 2*k2)*64 + c],
                                                        Wex[(g*16 + 2*k2 + 1)*64 + c]);
            wef[4 + g][k2] = __builtin_amdgcn_cvt_pkrtz(Weh[(g*16 + 2*k2)*64 + c],
                                                        Weh[(g*16 + 2*k2 + 1)*64 + c]);
        }
    }
    float xr8[8], acc[8], den[8];
    #pragma unroll
    for (int i = 0; i < 8; i++) {
        xr8[i] = (float)XR[((size_t)n*8 + i)*64 + c];
        acc[i] = 0.f;
        den[i] = 0.f;
    }
    int start = row_ptr[n];
    int end = row_ptr[n + 1];
    for (int base = start; base < end; base += 64) {
        int rem = end - base;
        int cnt = rem < 64 ? rem : 64;
        // pre-gather up to 64 edges' ids+srcs into lane registers (kills 2 of the
        // 3 dependent-load levels per edge)
        int eid_v = 0, src_v = 0;
        if (base + lane < end) {
            eid_v = sorted_eid[base + lane];
            src_v = src_idx[eid_v];
        }
        for (int j = 0; j < cnt; j++) {
            int eid = __builtin_amdgcn_readlane(eid_v, j);
            int sn  = __builtin_amdgcn_readlane(src_v, j);
            const float4* er4 = (const float4*)(e_buf + (size_t)eid * 16);
            float4 e0 = er4[0], e1 = er4[1], e2 = er4[2], e3 = er4[3];
            h2 es2[8];
            es2[0] = __builtin_amdgcn_cvt_pkrtz(e0.x, e0.y);
            es2[1] = __builtin_amdgcn_cvt_pkrtz(e0.z, e0.w);
            es2[2] = __builtin_amdgcn_cvt_pkrtz(e1.x, e1.y);
            es2[3] = __builtin_amdgcn_cvt_pkrtz(e1.z, e1.w);
            es2[4] = __builtin_amdgcn_cvt_pkrtz(e2.x, e2.y);
            es2[5] = __builtin_amdgcn_cvt_pkrtz(e2.z, e2.w);
            es2[6] = __builtin_amdgcn_cvt_pkrtz(e3.x, e3.y);
            es2[7] = __builtin_amdgcn_cvt_pkrtz(e3.z, e3.w);
            const f16* xlp = XL + (size_t)sn * 512 + c;
            #pragma unroll
            for (int inst = 0; inst < 8; inst++) {
                float xls = (float)xlp[inst * 64];
                float ee = 0.f;
                #pragma unroll
                for (int k2 = 0; k2 < 8; k2++)
                    ee = __builtin_amdgcn_fdot2(es2[k2], wef[inst][k2], ee, false);
                float m = xls + xr8[inst] + ee;
                float mr = fmaxf(m, 0.f) + 0.2f * fminf(m, 0.f);  // leaky_relu
                float t = mr * attv[inst];
                #pragma unroll
                for (int off = 16; off >= 1; off >>= 1) t += __shfl_xor(t, off);
                // scores are tiny (|s| << 1): exp without max-subtraction is exact-equivalent
                float p = __expf(t);
                den[inst] += p;
                acc[inst] = fmaf(p, xls, acc[inst]);
            }
        }
    }
    float gates[4];
    #pragma unroll
    for (int g = 0; g < 4; g++) {
        float ax = acc[g]     / (den[g]     + 1e-16f) + biasx[g*64 + c];
        float ah = acc[4 + g] / (den[4 + g] + 1e-16f) + biash[g*64 + c];
        gates[g] = ax + ah;
    }
    float it = 1.f / (1.f + __expf(-gates[0]));
    float ft = 1.f / (1.f + __expf(-gates[1]));
    float ot = 1.f / (1.f + __expf(-gates[2]));
    float gt = tanhf(gates[3]);
    float cp = c_prev[(size_t)n*64 + c];
    float ct = ft * cp + it * gt;
    float ht = ot * tanhf(ct);
    // LayerNorm over the 64 lanes (per-wave)
    float s1 = ht;
    #pragma unroll
    for (int off = 32; off >= 1; off >>= 1) s1 += __shfl_xor(s1, off);
    float mu = s1 * (1.f / 64.f);
    float d = ht - mu;
    float s2 = d * d;
    #pragma unroll
    for (int off = 32; off >= 1; off >>= 1) s2 += __shfl_xor(s2, off);
    float var = s2 * (1.f / 64.f);
    float y = d * rsqrtf(var + 1e-5f) * ln_g[c] + ln_b[c];
    out[(size_t)n*64 + c] = y;
    out[(size_t)(N_NODES + n)*64 + c] = ct;
}

extern "C" void kernel_launch(void* const* d_in, const int* in_sizes, int n_in,
                              void* d_out, int out_size, void* d_ws, size_t ws_size,
                              hipStream_t stream) {
    const float* x_t    = (const float*)d_in[0];
    const float* h_prev = (const float*)d_in[1];
    const float* c_prev = (const float*)d_in[2];
    const int*   ei     = (const int*)d_in[3];
    const float* eattr  = (const float*)d_in[4];
    const float* Wm1    = (const float*)d_in[5];
    const float* bm1    = (const float*)d_in[6];
    const float* Wm2    = (const float*)d_in[7];
    const float* bm2    = (const float*)d_in[8];
    const float* Wlx    = (const float*)d_in[9];
    const float* blx    = (const float*)d_in[10];
    const float* Wrx    = (const float*)d_in[11];
    const float* brx    = (const float*)d_in[12];
    const float* Wex    = (const float*)d_in[13];
    const float* attx   = (const float*)d_in[14];
    const float* biasx  = (const float*)d_in[15];
    const float* Wlh    = (const float*)d_in[16];
    const float* blh    = (const float*)d_in[17];
    const float* Wrh    = (const float*)d_in[18];
    const float* brh    = (const float*)d_in[19];
    const float* Weh    = (const float*)d_in[20];
    const float* atth   = (const float*)d_in[21];
    const float* biash  = (const float*)d_in[22];
    const float* ln_g   = (const float*)d_in[23];
    const float* ln_b   = (const float*)d_in[24];

    char* ws = (char*)d_ws;
    float* e_buf   = (float*)(ws + 0);            // 51,200,000 B
    f16*   XL      = (f16*)(ws + 51200000);       // 51,200,000 B
    f16*   XR      = (f16*)(ws + 102400000);      // 51,200,000 B
    int*   row_ptr = (int*)(ws + 153600000);      //    200,192 B
    int*   degcur  = (int*)(ws + 153800192);      //    200,192 B
    int*   sorted  = (int*)(ws + 154000384);      //  3,200,000 B
    // scan scratch overlaps `sorted` (dead before k_fill writes it)
    int*   scan_tmp  = (int*)(ws + 154000384);    //   200,704 B
    int*   partials  = (int*)(ws + 154000384 + 204800);  // 392 B

    const int* srcp = ei;
    const int* dstp = ei + N_EDGES;

    (void)hipMemsetAsync(degcur, 0, N_NODES * sizeof(int), stream);

    k_edge_mlp<<<(N_EDGES + 255) / 256, 256, 0, stream>>>(eattr, Wm1, bm1, Wm2, bm2, e_buf);
    k_node_feats<32><<<dim3(1024, 8), 64, 0, stream>>>(x_t, Wlx, blx, Wrx, brx, XL, XR, 0);
    k_node_feats<64><<<dim3(1024, 8), 64, 0, stream>>>(h_prev, Wlh, blh, Wrh, brh, XL, XR, 4);
    k_deg<<<(N_EDGES + 255) / 256, 256, 0, stream>>>(dstp, degcur);
    k_scan1<<<SCAN_NBLK, SCAN_B, 0, stream>>>(degcur, scan_tmp, partials);
    k_scan2<<<1, 64, 0, stream>>>(partials);
    k_scan3<<<SCAN_NBLK, SCAN_B, 0, stream>>>(scan_tmp, partials, row_ptr, degcur);
    k_fill<<<(N_EDGES + 255) / 256, 256, 0, stream>>>(dstp, row_ptr, degcur, sorted);
    k_gat_main<<<N_NODES / 4, 256, 0, stream>>>(srcp, e_buf, XL, XR, row_ptr, sorted,
                                                Wex, Weh, attx, atth, biasx, biash,
                                                c_prev, ln_g, ln_b, (float*)d_out);
}